// Round 1
// baseline (437.965 us; speedup 1.0000x reference)
//
#include <hip/hip_runtime.h>
#include <cstddef>

#define NB    4
#define NTOK  8192
#define DIMX  256
#define NH    8
#define HD    64
#define INNER 512
#define SPLIT 8
#define EPS   1e-5f

// ---------------------------------------------------------------------------
// Kernel 1: dots partials.  grid = NB*NH*SPLIT = 256 blocks, 256 threads.
// Each block: one (b, h, split of 1024 tokens). Computes k,v = z @ Wkv[head
// cols], instance-norm per token over 64 dims, accumulates dots += k^T v.
// ---------------------------------------------------------------------------
__global__ __launch_bounds__(256) void k_dots_partial(
    const float* __restrict__ z, const float* __restrict__ Wkv,
    float* __restrict__ partial)
{
  const int tid = threadIdx.x;
  const int bid = blockIdx.x;
  const int s = bid & (SPLIT - 1);
  const int h = (bid >> 3) & (NH - 1);
  const int b = bid >> 6;

  const int tx  = tid & 15;      // col group: cols {tx*4..+3} (k) and {64+tx*4..+3} (v)
  const int ty  = tid >> 4;      // token group: tokens ty*4..ty*4+3
  const int ty4 = ty * 4;
  const int tx4 = tx * 4;

  __shared__ float zs[64][20];      // z tile: 64 tokens x 16 k (pad 20)
  __shared__ float wsm[16][132];    // Wkv tile: 16 k x 128 cols (k|v halves)
  __shared__ float kv[64][132];     // kv tile (raw then normalized)
  __shared__ float mu_s[2][64];
  __shared__ float rs_s[2][64];

  float dacc[4][4];
#pragma unroll
  for (int i = 0; i < 4; ++i)
#pragma unroll
    for (int j = 0; j < 4; ++j) dacc[i][j] = 0.f;

  const float* zb = z + (size_t)b * NTOK * DIMX;

  // staging coordinates
  const int zr = tid >> 2;             // 64 rows, 4 threads/row
  const int zc = (tid & 3) * 4;        // 16 k-cols per chunk
  const int wk = tid >> 4;             // 16 k rows
  const int wj = (tid & 15) * 8;       // 128 cols, 8 per thread
  const int gcol0 = (wj < HD) ? (h * HD + wj) : (INNER + h * HD + (wj - HD));

  for (int tile = 0; tile < 16; ++tile) {
    const int tok0 = s * 1024 + tile * 64;
    float acc[4][8];
#pragma unroll
    for (int t = 0; t < 4; ++t)
#pragma unroll
      for (int c = 0; c < 8; ++c) acc[t][c] = 0.f;

    for (int kc = 0; kc < 16; ++kc) {
      float4 zv = *(const float4*)(zb + (size_t)(tok0 + zr) * DIMX + kc * 16 + zc);
      const float* wrow = Wkv + (size_t)(kc * 16 + wk) * (2 * INNER) + gcol0;
      float4 wv0 = *(const float4*)(wrow);
      float4 wv1 = *(const float4*)(wrow + 4);
      __syncthreads();
      *(float4*)&zs[zr][zc] = zv;
      *(float4*)&wsm[wk][wj] = wv0;
      *(float4*)&wsm[wk][wj + 4] = wv1;
      __syncthreads();
#pragma unroll
      for (int k4 = 0; k4 < 4; ++k4) {
        float4 zq0 = *(float4*)&zs[ty4 + 0][k4 * 4];
        float4 zq1 = *(float4*)&zs[ty4 + 1][k4 * 4];
        float4 zq2 = *(float4*)&zs[ty4 + 2][k4 * 4];
        float4 zq3 = *(float4*)&zs[ty4 + 3][k4 * 4];
        float zrg[4][4] = {{zq0.x, zq0.y, zq0.z, zq0.w},
                           {zq1.x, zq1.y, zq1.z, zq1.w},
                           {zq2.x, zq2.y, zq2.z, zq2.w},
                           {zq3.x, zq3.y, zq3.z, zq3.w}};
#pragma unroll
        for (int kk = 0; kk < 4; ++kk) {
          const int k = k4 * 4 + kk;
          float4 wa = *(float4*)&wsm[k][tx4];
          float4 wb = *(float4*)&wsm[k][64 + tx4];
          float w[8] = {wa.x, wa.y, wa.z, wa.w, wb.x, wb.y, wb.z, wb.w};
#pragma unroll
          for (int t = 0; t < 4; ++t) {
            const float zvv = zrg[t][kk];
#pragma unroll
            for (int c = 0; c < 8; ++c) acc[t][c] += zvv * w[c];
          }
        }
      }
    }

    // store raw kv tile
#pragma unroll
    for (int t = 0; t < 4; ++t) {
      *(float4*)&kv[ty4 + t][tx4]      = make_float4(acc[t][0], acc[t][1], acc[t][2], acc[t][3]);
      *(float4*)&kv[ty4 + t][64 + tx4] = make_float4(acc[t][4], acc[t][5], acc[t][6], acc[t][7]);
    }
    __syncthreads();

    // per-token stats over 64 dims (half 0 = k, half 1 = v)
    if (tid < 128) {
      const int token = tid & 63;
      const int half = tid >> 6;
      float s1 = 0.f, s2 = 0.f;
#pragma unroll
      for (int q4 = 0; q4 < 16; ++q4) {
        float4 vv = *(float4*)&kv[token][half * 64 + q4 * 4];
        s1 += vv.x + vv.y + vv.z + vv.w;
        s2 += vv.x * vv.x + vv.y * vv.y + vv.z * vv.z + vv.w * vv.w;
      }
      const float m = s1 * (1.f / 64.f);
      const float var = s2 * (1.f / 64.f) - m * m;
      mu_s[half][token] = m;
      rs_s[half][token] = rsqrtf(var + EPS);
    }
    __syncthreads();

    // normalize from registers, rewrite kv
#pragma unroll
    for (int t = 0; t < 4; ++t) {
      const int token = ty4 + t;
      const float mk = mu_s[0][token], rk = rs_s[0][token];
      const float mv = mu_s[1][token], rv = rs_s[1][token];
      *(float4*)&kv[token][tx4] =
          make_float4((acc[t][0] - mk) * rk, (acc[t][1] - mk) * rk,
                      (acc[t][2] - mk) * rk, (acc[t][3] - mk) * rk);
      *(float4*)&kv[token][64 + tx4] =
          make_float4((acc[t][4] - mv) * rv, (acc[t][5] - mv) * rv,
                      (acc[t][6] - mv) * rv, (acc[t][7] - mv) * rv);
    }
    __syncthreads();

    // dots accumulation: dots[d][e] += sum_t k[t][d] * v[t][e]
    {
      const int td = tid & 15;   // d group
      const int te = tid >> 4;   // e group
#pragma unroll 4
      for (int t = 0; t < 64; ++t) {
        float4 ka = *(float4*)&kv[t][td * 4];
        float4 va = *(float4*)&kv[t][64 + te * 4];
        float kk[4] = {ka.x, ka.y, ka.z, ka.w};
        float vv[4] = {va.x, va.y, va.z, va.w};
#pragma unroll
        for (int i = 0; i < 4; ++i)
#pragma unroll
          for (int j = 0; j < 4; ++j) dacc[i][j] += kk[i] * vv[j];
      }
    }
    __syncthreads();
  }

  const int td = tid & 15;
  const int te = tid >> 4;
  float* pb = partial + ((size_t)((b * NH + h) * SPLIT + s)) * 4096;
#pragma unroll
  for (int i = 0; i < 4; ++i) {
    *(float4*)&pb[(td * 4 + i) * 64 + te * 4] =
        make_float4(dacc[i][0], dacc[i][1], dacc[i][2], dacc[i][3]);
  }
}

// ---------------------------------------------------------------------------
// Kernel 2a: reduce split partials -> dots (scaled by 1/n2). grid 512x256.
// ---------------------------------------------------------------------------
__global__ __launch_bounds__(256) void k_reduce(
    const float* __restrict__ partial, float* __restrict__ dots)
{
  const int idx = blockIdx.x * 256 + threadIdx.x;   // 131072 total
  const int bh = idx >> 12;
  const int de = idx & 4095;
  const float* p = partial + (size_t)bh * SPLIT * 4096 + de;
  float s = 0.f;
#pragma unroll
  for (int i = 0; i < SPLIT; ++i) s += p[(size_t)i * 4096];
  dots[idx] = s * (1.f / (float)NTOK);
}

// ---------------------------------------------------------------------------
// Kernel 2b: tmp[b][r][c] = sum_j dots[b][r>>6][r&63][j] * Wout[(r>>6)*64+j][c]
// grid = NB*128 blocks (4 rows each), 256 threads (c).
// ---------------------------------------------------------------------------
__global__ __launch_bounds__(256) void k_bdwout(
    const float* __restrict__ dots, const float* __restrict__ Wout,
    float* __restrict__ tmp)
{
  const int bid = blockIdx.x;
  const int b = bid >> 7;
  const int r4 = (bid & 127) * 4;
  const int h = r4 >> 6;
  const int c = threadIdx.x;
  const float* dr = dots + (size_t)(b * NH + h) * 4096 + (size_t)(r4 & 63) * 64;
  float a0 = 0.f, a1 = 0.f, a2 = 0.f, a3 = 0.f;
  for (int j = 0; j < 64; ++j) {
    const float w = Wout[(size_t)(h * 64 + j) * DIMX + c];
    a0 += dr[j] * w;
    a1 += dr[64 + j] * w;
    a2 += dr[128 + j] * w;
    a3 += dr[192 + j] * w;
  }
  float* tb = tmp + ((size_t)b * INNER + r4) * DIMX + c;
  tb[0] = a0; tb[DIMX] = a1; tb[2 * DIMX] = a2; tb[3 * DIMX] = a3;
}

// ---------------------------------------------------------------------------
// Kernel 2c: W_eff[b][r][c] = sum_k Wq[r][k] * tmp[b][k][c]
// grid = NB*64 blocks (4 rows each), 256 threads (c).
// ---------------------------------------------------------------------------
__global__ __launch_bounds__(256) void k_weff(
    const float* __restrict__ Wq, const float* __restrict__ tmp,
    float* __restrict__ W_eff)
{
  const int bid = blockIdx.x;
  const int b = bid >> 6;
  const int r4 = (bid & 63) * 4;
  const int c = threadIdx.x;
  const float* tb = tmp + (size_t)b * INNER * DIMX + c;
  float a0 = 0.f, a1 = 0.f, a2 = 0.f, a3 = 0.f;
  for (int k = 0; k < INNER; ++k) {
    const float t = tb[(size_t)k * DIMX];
    a0 += Wq[(size_t)(r4 + 0) * INNER + k] * t;
    a1 += Wq[(size_t)(r4 + 1) * INNER + k] * t;
    a2 += Wq[(size_t)(r4 + 2) * INNER + k] * t;
    a3 += Wq[(size_t)(r4 + 3) * INNER + k] * t;
  }
  float* wb = W_eff + ((size_t)b * DIMX + r4) * DIMX + c;
  wb[0] = a0; wb[DIMX] = a1; wb[2 * DIMX] = a2; wb[3 * DIMX] = a3;
}

// ---------------------------------------------------------------------------
// Kernel 3: out[b] = x[b] @ W_eff[b] + bout.  128x128 tile per block,
// grid = NB * 64 * 2 = 512 blocks, 256 threads, 8x8 per thread.
// ---------------------------------------------------------------------------
__global__ __launch_bounds__(256) void k_out(
    const float* __restrict__ x, const float* __restrict__ W_eff,
    const float* __restrict__ bout, float* __restrict__ out)
{
  const int tid = threadIdx.x;
  const int bid = blockIdx.x;
  const int ct = bid & 1;
  const int mt = (bid >> 1) & 63;
  const int b = bid >> 7;
  const int tok0 = mt * 128;
  const int col0 = ct * 128;

  const int tx = tid & 15;   // col group: {tx*4..+3} and {64+tx*4..+3}
  const int ty = tid >> 4;   // token rows: ty + 16*t, t=0..7
  const int tx4 = tx * 4;

  __shared__ float xs[128][20];
  __shared__ float wsm[16][132];

  float acc[8][8];
#pragma unroll
  for (int t = 0; t < 8; ++t)
#pragma unroll
    for (int c = 0; c < 8; ++c) acc[t][c] = 0.f;

  const float* xb = x + (size_t)b * NTOK * DIMX;
  const float* wbase = W_eff + (size_t)b * DIMX * DIMX;

  const int xr = tid >> 1;            // 128 rows, 2 threads/row
  const int xc = (tid & 1) * 8;       // 16 k-cols per chunk, 8 per thread
  const int wk = tid >> 4;
  const int wj = (tid & 15) * 8;

  for (int kc = 0; kc < 16; ++kc) {
    float4 xv0 = *(const float4*)(xb + (size_t)(tok0 + xr) * DIMX + kc * 16 + xc);
    float4 xv1 = *(const float4*)(xb + (size_t)(tok0 + xr) * DIMX + kc * 16 + xc + 4);
    const float* wrow = wbase + (size_t)(kc * 16 + wk) * DIMX + col0 + wj;
    float4 wv0 = *(const float4*)(wrow);
    float4 wv1 = *(const float4*)(wrow + 4);
    __syncthreads();
    *(float4*)&xs[xr][xc] = xv0;
    *(float4*)&xs[xr][xc + 4] = xv1;
    *(float4*)&wsm[wk][wj] = wv0;
    *(float4*)&wsm[wk][wj + 4] = wv1;
    __syncthreads();
#pragma unroll
    for (int k4 = 0; k4 < 4; ++k4) {
      float xq[8][4];
#pragma unroll
      for (int t = 0; t < 8; ++t) {
        float4 v = *(float4*)&xs[ty + 16 * t][k4 * 4];
        xq[t][0] = v.x; xq[t][1] = v.y; xq[t][2] = v.z; xq[t][3] = v.w;
      }
#pragma unroll
      for (int kk = 0; kk < 4; ++kk) {
        const int k = k4 * 4 + kk;
        float4 wa = *(float4*)&wsm[k][tx4];
        float4 wb = *(float4*)&wsm[k][64 + tx4];
        float w[8] = {wa.x, wa.y, wa.z, wa.w, wb.x, wb.y, wb.z, wb.w};
#pragma unroll
        for (int t = 0; t < 8; ++t) {
          const float xvv = xq[t][kk];
#pragma unroll
          for (int c = 0; c < 8; ++c) acc[t][c] += xvv * w[c];
        }
      }
    }
  }

  float4 ba = *(const float4*)(bout + col0 + tx4);
  float4 bb = *(const float4*)(bout + col0 + 64 + tx4);
#pragma unroll
  for (int t = 0; t < 8; ++t) {
    const int row = tok0 + ty + 16 * t;
    float* op = out + ((size_t)b * NTOK + row) * DIMX + col0;
    *(float4*)(op + tx4) = make_float4(acc[t][0] + ba.x, acc[t][1] + ba.y,
                                       acc[t][2] + ba.z, acc[t][3] + ba.w);
    *(float4*)(op + 64 + tx4) = make_float4(acc[t][4] + bb.x, acc[t][5] + bb.y,
                                            acc[t][6] + bb.z, acc[t][7] + bb.w);
  }
}

// ---------------------------------------------------------------------------
extern "C" void kernel_launch(void* const* d_in, const int* in_sizes, int n_in,
                              void* d_out, int out_size, void* d_ws, size_t ws_size,
                              hipStream_t stream) {
  const float* x    = (const float*)d_in[0];
  const float* z    = (const float*)d_in[1];
  const float* Wq   = (const float*)d_in[2];
  const float* Wkv  = (const float*)d_in[3];
  const float* Wout = (const float*)d_in[4];
  const float* bout = (const float*)d_in[5];
  float* out = (float*)d_out;

  float* ws      = (float*)d_ws;
  float* partial = ws;                          // 4*8*8*4096   = 1,048,576 f
  float* dots    = partial + (size_t)NB * NH * SPLIT * 4096;  // 131,072 f
  float* tmp     = dots + (size_t)NB * NH * 4096;             // 524,288 f
  float* W_eff   = tmp + (size_t)NB * INNER * DIMX;           // 262,144 f
  // total workspace: ~7.5 MB

  k_dots_partial<<<NB * NH * SPLIT, 256, 0, stream>>>(z, Wkv, partial);
  k_reduce<<<512, 256, 0, stream>>>(partial, dots);
  k_bdwout<<<NB * 128, 256, 0, stream>>>(dots, Wout, tmp);
  k_weff<<<NB * 64, 256, 0, stream>>>(Wq, tmp, W_eff);
  k_out<<<NB * 64 * 2, 256, 0, stream>>>(x, W_eff, bout, out);
}

// Round 2
// 143.853 us; speedup vs baseline: 3.0445x; 3.0445x over previous
//
#include <hip/hip_runtime.h>
#include <cstddef>

#define NB    4
#define NTOK  8192
#define DIMX  256
#define NH    8
#define HD    64
#define INNER 512
#define SPLIT 8
#define EPS   1e-5f

typedef __attribute__((ext_vector_type(8))) short short8;
typedef __attribute__((ext_vector_type(4))) float f32x4;

__device__ __forceinline__ unsigned short f2bf(float f) {
  union { float f; unsigned u; } v; v.f = f;
  unsigned r = v.u + 0x7fffu + ((v.u >> 16) & 1u);   // RNE
  return (unsigned short)(r >> 16);
}

// ---------------------------------------------------------------------------
// Wkv [256][1024] fp32  ->  WkvT [1024][256] bf16
// ---------------------------------------------------------------------------
__global__ __launch_bounds__(256) void k_wkvT(
    const float* __restrict__ Wkv, unsigned short* __restrict__ wkvT)
{
  const int c = blockIdx.x;      // 0..1023
  const int r = threadIdx.x;     // 0..255
  wkvT[(size_t)c * DIMX + r] = f2bf(Wkv[(size_t)r * (2 * INNER) + c]);
}

// ---------------------------------------------------------------------------
// dots partials via MFMA. grid = NB*NH*SPLIT = 256 blocks, 256 threads.
// Per block: tokens [s*1024, s*1024+1024), one (b,h).
// Computes kvT (128 dims x 64 tokens tiles), instance-norm per token,
// accumulates dots[64][64] += k_hat * v_hat^T (contraction over tokens).
// ---------------------------------------------------------------------------
__global__ __launch_bounds__(256) void k_dots_mfma(
    const float* __restrict__ z, const unsigned short* __restrict__ wkvT,
    float* __restrict__ partial)
{
  const int tid  = threadIdx.x;
  const int lane = tid & 63;
  const int w    = tid >> 6;       // wave 0..3
  const int l15  = lane & 15;
  const int lg   = lane >> 4;      // 0..3

  const int bid = blockIdx.x;
  const int s = bid & (SPLIT - 1);
  const int h = (bid >> 3) & (NH - 1);
  const int b = bid >> 6;

  __shared__ unsigned short zs[64][264];   // 64 tok x 256 k bf16, stride 528B
  __shared__ unsigned short kv2[128][72];  // 128 dims x 64 tok bf16, stride 144B
  __shared__ float sum1[4][64];
  __shared__ float sum2[4][64];

  // A-fragments: WkvT slice for this wave's 32 dims, all 8 K-steps, in regs.
  short8 awf[2][8];
#pragma unroll
  for (int mf = 0; mf < 2; ++mf) {
    const int dim = w * 32 + mf * 16 + l15;                 // 0..127
    const int gd = (dim < HD) ? (h * HD + dim) : (INNER + h * HD + (dim - HD));
    const unsigned short* base = wkvT + (size_t)gd * DIMX + lg * 8;
#pragma unroll
    for (int kk = 0; kk < 8; ++kk)
      awf[mf][kk] = *(const short8*)(base + kk * 32);
  }

  f32x4 dacc[4];
#pragma unroll
  for (int nf = 0; nf < 4; ++nf) dacc[nf] = (f32x4){0.f, 0.f, 0.f, 0.f};

  const int zr = tid >> 2;        // 0..63 token row for staging
  const int zq = tid & 3;         // col quarter

  for (int tile = 0; tile < 16; ++tile) {
    const int tok0 = s * 1024 + tile * 64;

    // ---- stage z tile (fp32 -> bf16) into LDS ----
    {
      const float* zrow = z + ((size_t)b * NTOK + tok0 + zr) * DIMX + zq * 64;
#pragma unroll
      for (int j = 0; j < 8; ++j) {
        float4 v0 = *(const float4*)(zrow + j * 8);
        float4 v1 = *(const float4*)(zrow + j * 8 + 4);
        short8 p;
        p[0] = (short)f2bf(v0.x); p[1] = (short)f2bf(v0.y);
        p[2] = (short)f2bf(v0.z); p[3] = (short)f2bf(v0.w);
        p[4] = (short)f2bf(v1.x); p[5] = (short)f2bf(v1.y);
        p[6] = (short)f2bf(v1.z); p[7] = (short)f2bf(v1.w);
        *(short8*)&zs[zr][zq * 64 + j * 8] = p;
      }
    }
    __syncthreads();   // B1: zs ready

    // ---- phase 1: kvT_raw = WkvT_slice @ zT  (M=32 dims/wave, N=64 tok) ----
    f32x4 acc[2][4];
#pragma unroll
    for (int mf = 0; mf < 2; ++mf)
#pragma unroll
      for (int nf = 0; nf < 4; ++nf) acc[mf][nf] = (f32x4){0.f, 0.f, 0.f, 0.f};

    for (int kk = 0; kk < 8; ++kk) {
      short8 bfr[4];
#pragma unroll
      for (int nf = 0; nf < 4; ++nf)
        bfr[nf] = *(const short8*)&zs[nf * 16 + l15][kk * 32 + lg * 8];
#pragma unroll
      for (int mf = 0; mf < 2; ++mf)
#pragma unroll
        for (int nf = 0; nf < 4; ++nf)
          acc[mf][nf] = __builtin_amdgcn_mfma_f32_16x16x32_bf16(
              awf[mf][kk], bfr[nf], acc[mf][nf], 0, 0, 0);
    }

    // ---- per-token stats (this wave's 32 rows), cross-lane-group reduce ----
    float s1[4], s2[4];
#pragma unroll
    for (int nf = 0; nf < 4; ++nf) {
      float a = 0.f, q = 0.f;
#pragma unroll
      for (int mf = 0; mf < 2; ++mf)
#pragma unroll
        for (int r = 0; r < 4; ++r) {
          float v = acc[mf][nf][r];
          a += v; q += v * v;
        }
      a += __shfl_xor(a, 16); a += __shfl_xor(a, 32);
      q += __shfl_xor(q, 16); q += __shfl_xor(q, 32);
      s1[nf] = a; s2[nf] = q;
    }
    if (lg == 0) {
#pragma unroll
      for (int nf = 0; nf < 4; ++nf) {
        sum1[w][nf * 16 + l15] = s1[nf];
        sum2[w][nf * 16 + l15] = s2[nf];
      }
    }
    __syncthreads();   // B2: sums ready

    // ---- combine with partner wave, normalize, write kv2 (bf16) ----
    const int p = w ^ 1;
    float mu[4], rs[4];
#pragma unroll
    for (int nf = 0; nf < 4; ++nf) {
      float t1 = s1[nf] + sum1[p][nf * 16 + l15];
      float t2 = s2[nf] + sum2[p][nf * 16 + l15];
      float m = t1 * (1.f / 64.f);
      float var = t2 * (1.f / 64.f) - m * m;
      mu[nf] = m;
      rs[nf] = rsqrtf(var + EPS);
    }
#pragma unroll
    for (int mf = 0; mf < 2; ++mf)
#pragma unroll
      for (int nf = 0; nf < 4; ++nf)
#pragma unroll
        for (int r = 0; r < 4; ++r) {
          float v = (acc[mf][nf][r] - mu[nf]) * rs[nf];
          kv2[w * 32 + mf * 16 + lg * 4 + r][nf * 16 + l15] = f2bf(v);
        }
    __syncthreads();   // B3: kv2 ready

    // ---- phase 3: dots += k_hat @ v_hat^T (contraction over 64 tokens) ----
#pragma unroll
    for (int ks = 0; ks < 2; ++ks) {
      short8 a2 = *(const short8*)&kv2[w * 16 + l15][ks * 32 + lg * 8];
#pragma unroll
      for (int nf = 0; nf < 4; ++nf) {
        short8 b2 = *(const short8*)&kv2[64 + nf * 16 + l15][ks * 32 + lg * 8];
        dacc[nf] = __builtin_amdgcn_mfma_f32_16x16x32_bf16(a2, b2, dacc[nf], 0, 0, 0);
      }
    }
  }

  // dots rows d = w*16 + lg*4 + r ; cols e = nf*16 + l15
  float* pb = partial + ((size_t)((b * NH + h) * SPLIT + s)) * 4096;
#pragma unroll
  for (int nf = 0; nf < 4; ++nf)
#pragma unroll
    for (int r = 0; r < 4; ++r)
      pb[(w * 16 + lg * 4 + r) * 64 + nf * 16 + l15] = dacc[nf][r];
}

// ---------------------------------------------------------------------------
// reduce split partials -> dots (scaled by 1/n2). 131072 elems.
// ---------------------------------------------------------------------------
__global__ __launch_bounds__(256) void k_reduce(
    const float* __restrict__ partial, float* __restrict__ dots)
{
  const int idx = blockIdx.x * 256 + threadIdx.x;
  const int bh = idx >> 12;
  const int de = idx & 4095;
  const float* p = partial + (size_t)bh * SPLIT * 4096 + de;
  float s = 0.f;
#pragma unroll
  for (int i = 0; i < SPLIT; ++i) s += p[(size_t)i * 4096];
  dots[idx] = s * (1.f / (float)NTOK);
}

// ---------------------------------------------------------------------------
// tmp[b][r][c] = sum_j dots[b][r>>6][r&63][j] * Wout[(r>>6)*64+j][c]
// ---------------------------------------------------------------------------
__global__ __launch_bounds__(256) void k_bdwout(
    const float* __restrict__ dots, const float* __restrict__ Wout,
    float* __restrict__ tmp)
{
  const int bid = blockIdx.x;
  const int b = bid >> 7;
  const int r4 = (bid & 127) * 4;
  const int h = r4 >> 6;
  const int c = threadIdx.x;
  const float* dr = dots + (size_t)(b * NH + h) * 4096 + (size_t)(r4 & 63) * 64;
  float a0 = 0.f, a1 = 0.f, a2 = 0.f, a3 = 0.f;
  for (int j = 0; j < 64; ++j) {
    const float wv = Wout[(size_t)(h * 64 + j) * DIMX + c];
    a0 += dr[j] * wv;
    a1 += dr[64 + j] * wv;
    a2 += dr[128 + j] * wv;
    a3 += dr[192 + j] * wv;
  }
  float* tb = tmp + ((size_t)b * INNER + r4) * DIMX + c;
  tb[0] = a0; tb[DIMX] = a1; tb[2 * DIMX] = a2; tb[3 * DIMX] = a3;
}

// ---------------------------------------------------------------------------
// W_effT[b][c][r] (bf16) = sum_k Wq[r][k] * tmp[b][k][c]
// ---------------------------------------------------------------------------
__global__ __launch_bounds__(256) void k_weff(
    const float* __restrict__ Wq, const float* __restrict__ tmp,
    unsigned short* __restrict__ weffT)
{
  const int bid = blockIdx.x;
  const int b = bid >> 6;
  const int r4 = (bid & 63) * 4;
  const int c = threadIdx.x;
  const float* tb = tmp + (size_t)b * INNER * DIMX + c;
  float a0 = 0.f, a1 = 0.f, a2 = 0.f, a3 = 0.f;
  for (int k = 0; k < INNER; ++k) {
    const float t = tb[(size_t)k * DIMX];
    a0 += Wq[(size_t)(r4 + 0) * INNER + k] * t;
    a1 += Wq[(size_t)(r4 + 1) * INNER + k] * t;
    a2 += Wq[(size_t)(r4 + 2) * INNER + k] * t;
    a3 += Wq[(size_t)(r4 + 3) * INNER + k] * t;
  }
  unsigned short* wb = weffT + ((size_t)b * DIMX + c) * DIMX + r4;
  wb[0] = f2bf(a0); wb[1] = f2bf(a1); wb[2] = f2bf(a2); wb[3] = f2bf(a3);
}

// ---------------------------------------------------------------------------
// out[b] = x[b] @ W_eff[b] + bout via MFMA. grid = NB*128, 256 thr.
// Block: 64 tokens x 256 cols. Wave w: tokens [tok0+16w, +16), all cols.
// x converted fp32->bf16 in-register.
// ---------------------------------------------------------------------------
__global__ __launch_bounds__(256) void k_out_mfma(
    const float* __restrict__ x, const unsigned short* __restrict__ weffT,
    const float* __restrict__ bout, float* __restrict__ out)
{
  const int tid  = threadIdx.x;
  const int lane = tid & 63;
  const int w    = tid >> 6;
  const int l15  = lane & 15;
  const int lg   = lane >> 4;

  const int bid = blockIdx.x;
  const int mt = bid & 127;
  const int b  = bid >> 7;
  const int tok0 = mt * 64;

  f32x4 acc[16];
#pragma unroll
  for (int nf = 0; nf < 16; ++nf) acc[nf] = (f32x4){0.f, 0.f, 0.f, 0.f};

  const float* xr = x + ((size_t)b * NTOK + tok0 + w * 16 + l15) * DIMX + lg * 8;
  const unsigned short* wb = weffT + (size_t)b * DIMX * DIMX + lg * 8;

  for (int kk = 0; kk < 8; ++kk) {
    float4 xa = *(const float4*)(xr + kk * 32);
    float4 xb = *(const float4*)(xr + kk * 32 + 4);
    short8 a;
    a[0] = (short)f2bf(xa.x); a[1] = (short)f2bf(xa.y);
    a[2] = (short)f2bf(xa.z); a[3] = (short)f2bf(xa.w);
    a[4] = (short)f2bf(xb.x); a[5] = (short)f2bf(xb.y);
    a[6] = (short)f2bf(xb.z); a[7] = (short)f2bf(xb.w);
#pragma unroll
    for (int nf = 0; nf < 16; ++nf) {
      short8 bf = *(const short8*)(wb + (size_t)(nf * 16 + l15) * DIMX + kk * 32);
      acc[nf] = __builtin_amdgcn_mfma_f32_16x16x32_bf16(a, bf, acc[nf], 0, 0, 0);
    }
  }

#pragma unroll
  for (int nf = 0; nf < 16; ++nf) {
    const float bias = bout[nf * 16 + l15];
#pragma unroll
    for (int r = 0; r < 4; ++r) {
      const int row = tok0 + w * 16 + lg * 4 + r;
      out[((size_t)b * NTOK + row) * DIMX + nf * 16 + l15] = acc[nf][r] + bias;
    }
  }
}

// ---------------------------------------------------------------------------
extern "C" void kernel_launch(void* const* d_in, const int* in_sizes, int n_in,
                              void* d_out, int out_size, void* d_ws, size_t ws_size,
                              hipStream_t stream) {
  const float* x    = (const float*)d_in[0];
  const float* z    = (const float*)d_in[1];
  const float* Wq   = (const float*)d_in[2];
  const float* Wkv  = (const float*)d_in[3];
  const float* Wout = (const float*)d_in[4];
  const float* bout = (const float*)d_in[5];
  float* out = (float*)d_out;

  float* ws      = (float*)d_ws;
  float* partial = ws;                                        // 1,048,576 f (4MB)
  float* dots    = partial + (size_t)NB * NH * SPLIT * 4096;  // 131,072 f
  float* tmp     = dots + (size_t)NB * NH * 4096;             // 524,288 f
  unsigned short* wkvT  = (unsigned short*)(tmp + (size_t)NB * INNER * DIMX); // 262,144 us
  unsigned short* weffT = wkvT + (size_t)(2 * INNER) * DIMX;                  // 262,144 us
  // total ~7.5 MB

  k_wkvT<<<2 * INNER, 256, 0, stream>>>(Wkv, wkvT);
  k_dots_mfma<<<NB * NH * SPLIT, 256, 0, stream>>>(z, wkvT, partial);
  k_reduce<<<512, 256, 0, stream>>>(partial, dots);
  k_bdwout<<<NB * 128, 256, 0, stream>>>(dots, Wout, tmp);
  k_weff<<<NB * 64, 256, 0, stream>>>(Wq, tmp, weffT);
  k_out_mfma<<<NB * 128, 256, 0, stream>>>(x, weffT, bout, out);
}

// Round 4
// 106.980 us; speedup vs baseline: 4.0939x; 1.3447x over previous
//
#include <hip/hip_runtime.h>
#include <cstddef>

#define NB    4
#define NTOK  8192
#define DIMX  256
#define NH    8
#define HD    64
#define INNER 512
#define SPLIT 16
#define EPS   1e-5f

typedef __attribute__((ext_vector_type(8))) short short8;
typedef __attribute__((ext_vector_type(4))) float f32x4;

__device__ __forceinline__ unsigned short f2bf(float f) {
  union { float f; unsigned u; } v; v.f = f;
  unsigned r = v.u + 0x7fffu + ((v.u >> 16) & 1u);   // RNE
  return (unsigned short)(r >> 16);
}

// ---------------------------------------------------------------------------
// z fp32 [4*8192*256] -> bf16. 16 elems/thread, 2048 blocks.
// ---------------------------------------------------------------------------
__global__ __launch_bounds__(256) void k_zbf(
    const float* __restrict__ z, unsigned short* __restrict__ zb)
{
  const size_t i = ((size_t)blockIdx.x * 256 + threadIdx.x) * 16;
  float4 a0 = *(const float4*)(z + i);
  float4 a1 = *(const float4*)(z + i + 4);
  float4 a2 = *(const float4*)(z + i + 8);
  float4 a3 = *(const float4*)(z + i + 12);
  short8 p0, p1;
  p0[0] = (short)f2bf(a0.x); p0[1] = (short)f2bf(a0.y);
  p0[2] = (short)f2bf(a0.z); p0[3] = (short)f2bf(a0.w);
  p0[4] = (short)f2bf(a1.x); p0[5] = (short)f2bf(a1.y);
  p0[6] = (short)f2bf(a1.z); p0[7] = (short)f2bf(a1.w);
  p1[0] = (short)f2bf(a2.x); p1[1] = (short)f2bf(a2.y);
  p1[2] = (short)f2bf(a2.z); p1[3] = (short)f2bf(a2.w);
  p1[4] = (short)f2bf(a3.x); p1[5] = (short)f2bf(a3.y);
  p1[6] = (short)f2bf(a3.z); p1[7] = (short)f2bf(a3.w);
  *(short8*)(zb + i) = p0;
  *(short8*)(zb + i + 8) = p1;
}

// ---------------------------------------------------------------------------
// Wkv [256][1024] fp32 -> WkvT [1024][256] bf16, LDS tile transpose.
// grid 64 blocks: 4 row-tiles x 16 col-tiles of 64x64.
// ---------------------------------------------------------------------------
__global__ __launch_bounds__(256) void k_wkvT(
    const float* __restrict__ Wkv, unsigned short* __restrict__ wkvT)
{
  const int tid = threadIdx.x;
  const int r0 = (blockIdx.x & 3) * 64;
  const int c0 = (blockIdx.x >> 2) * 64;
  __shared__ unsigned short t[64][68];

  const int r = tid >> 2;
  const int c4 = (tid & 3) * 16;
#pragma unroll
  for (int j = 0; j < 4; ++j) {
    float4 v = *(const float4*)(Wkv + (size_t)(r0 + r) * (2 * INNER) + c0 + c4 + j * 4);
    t[r][c4 + j * 4 + 0] = f2bf(v.x);
    t[r][c4 + j * 4 + 1] = f2bf(v.y);
    t[r][c4 + j * 4 + 2] = f2bf(v.z);
    t[r][c4 + j * 4 + 3] = f2bf(v.w);
  }
  __syncthreads();
  const int cc = tid >> 2;
  const int rr4 = (tid & 3) * 16;
  short8 o0, o1;
#pragma unroll
  for (int i = 0; i < 8; ++i) o0[i] = (short)t[rr4 + i][cc];
#pragma unroll
  for (int i = 0; i < 8; ++i) o1[i] = (short)t[rr4 + 8 + i][cc];
  unsigned short* dst = wkvT + (size_t)(c0 + cc) * DIMX + r0 + rr4;
  *(short8*)(dst) = o0;
  *(short8*)(dst + 8) = o1;
}

// ---------------------------------------------------------------------------
// dots partials via MFMA. grid = NB*NH*SPLIT = 512 blocks, 256 threads.
// Per block: 512 tokens (8 tiles of 64), one (b,h).
// ---------------------------------------------------------------------------
__global__ __launch_bounds__(256) void k_dots_mfma(
    const unsigned short* __restrict__ zb, const unsigned short* __restrict__ wkvT,
    float* __restrict__ partial)
{
  const int tid  = threadIdx.x;
  const int lane = tid & 63;
  const int w    = tid >> 6;       // wave 0..3
  const int l15  = lane & 15;
  const int lg   = lane >> 4;      // 0..3

  const int bid = blockIdx.x;
  const int s = bid & (SPLIT - 1);
  const int h = (bid >> 4) & (NH - 1);
  const int b = bid >> 7;

  __shared__ unsigned short zs[64][264];   // 64 tok x 256 dims bf16
  __shared__ unsigned short kv2[128][72];  // 128 dims x 64 tok bf16
  __shared__ float sum1[4][64];
  __shared__ float sum2[4][64];

  // A-fragments: WkvT slice for this wave's 32 dims, all 8 K-steps.
  short8 awf[2][8];
#pragma unroll
  for (int mf = 0; mf < 2; ++mf) {
    const int dim = w * 32 + mf * 16 + l15;
    const int gd = (dim < HD) ? (h * HD + dim) : (INNER + h * HD + (dim - HD));
    const unsigned short* base = wkvT + (size_t)gd * DIMX + lg * 8;
#pragma unroll
    for (int kk = 0; kk < 8; ++kk)
      awf[mf][kk] = *(const short8*)(base + kk * 32);
  }

  f32x4 dacc[4];
#pragma unroll
  for (int nf = 0; nf < 4; ++nf) dacc[nf] = (f32x4){0.f, 0.f, 0.f, 0.f};

  const int zr = tid >> 2;
  const int zq = tid & 3;
  const unsigned short* zbase = zb + ((size_t)b * NTOK + s * 512 + zr) * DIMX + zq * 64;

  // prologue: stage tile 0  (64 bf16 per thread = 8 x short8)
  {
    short8 pre[8];
#pragma unroll
    for (int j = 0; j < 8; ++j) pre[j] = *(const short8*)(zbase + j * 8);
#pragma unroll
    for (int j = 0; j < 8; ++j) *(short8*)&zs[zr][zq * 64 + j * 8] = pre[j];
  }
  __syncthreads();

  for (int tile = 0; tile < 8; ++tile) {
    // prefetch next z tile into regs (issued before compute; latency hidden)
    short8 pre[8];
    if (tile < 7) {
      const unsigned short* src = zbase + (size_t)(tile + 1) * 64 * DIMX;
#pragma unroll
      for (int j = 0; j < 8; ++j) pre[j] = *(const short8*)(src + j * 8);
    }

    // ---- phase 1: kvT_raw = WkvT_slice @ zT ----
    f32x4 acc[2][4];
#pragma unroll
    for (int mf = 0; mf < 2; ++mf)
#pragma unroll
      for (int nf = 0; nf < 4; ++nf) acc[mf][nf] = (f32x4){0.f, 0.f, 0.f, 0.f};

#pragma unroll
    for (int kk = 0; kk < 8; ++kk) {
      short8 bfr[4];
#pragma unroll
      for (int nf = 0; nf < 4; ++nf)
        bfr[nf] = *(const short8*)&zs[nf * 16 + l15][kk * 32 + lg * 8];
#pragma unroll
      for (int mf = 0; mf < 2; ++mf)
#pragma unroll
        for (int nf = 0; nf < 4; ++nf)
          acc[mf][nf] = __builtin_amdgcn_mfma_f32_16x16x32_bf16(
              awf[mf][kk], bfr[nf], acc[mf][nf], 0, 0, 0);
    }

    // ---- per-token stats ----
    float s1[4], s2[4];
#pragma unroll
    for (int nf = 0; nf < 4; ++nf) {
      float a = 0.f, q = 0.f;
#pragma unroll
      for (int mf = 0; mf < 2; ++mf)
#pragma unroll
        for (int r = 0; r < 4; ++r) {
          float v = acc[mf][nf][r];
          a += v; q += v * v;
        }
      a += __shfl_xor(a, 16); a += __shfl_xor(a, 32);
      q += __shfl_xor(q, 16); q += __shfl_xor(q, 32);
      s1[nf] = a; s2[nf] = q;
    }
    if (lg == 0) {
#pragma unroll
      for (int nf = 0; nf < 4; ++nf) {
        sum1[w][nf * 16 + l15] = s1[nf];
        sum2[w][nf * 16 + l15] = s2[nf];
      }
    }
    __syncthreads();   // B2: sums ready; all waves done reading zs

    // stage next z tile into zs (zs idle until after B3)
    if (tile < 7) {
#pragma unroll
      for (int j = 0; j < 8; ++j) *(short8*)&zs[zr][zq * 64 + j * 8] = pre[j];
    }

    // ---- normalize, write kv2 ----
    const int p = w ^ 1;
    float mu[4], rs[4];
#pragma unroll
    for (int nf = 0; nf < 4; ++nf) {
      float t1 = s1[nf] + sum1[p][nf * 16 + l15];
      float t2 = s2[nf] + sum2[p][nf * 16 + l15];
      float m = t1 * (1.f / 64.f);
      float var = t2 * (1.f / 64.f) - m * m;
      mu[nf] = m;
      rs[nf] = rsqrtf(var + EPS);
    }
#pragma unroll
    for (int mf = 0; mf < 2; ++mf)
#pragma unroll
      for (int nf = 0; nf < 4; ++nf)
#pragma unroll
        for (int r = 0; r < 4; ++r) {
          float v = (acc[mf][nf][r] - mu[nf]) * rs[nf];
          kv2[w * 32 + mf * 16 + lg * 4 + r][nf * 16 + l15] = f2bf(v);
        }
    __syncthreads();   // B3: kv2 + next zs ready

    // ---- phase 3: dots += k_hat @ v_hat^T ----
#pragma unroll
    for (int ks = 0; ks < 2; ++ks) {
      short8 a2 = *(const short8*)&kv2[w * 16 + l15][ks * 32 + lg * 8];
#pragma unroll
      for (int nf = 0; nf < 4; ++nf) {
        short8 b2 = *(const short8*)&kv2[64 + nf * 16 + l15][ks * 32 + lg * 8];
        dacc[nf] = __builtin_amdgcn_mfma_f32_16x16x32_bf16(a2, b2, dacc[nf], 0, 0, 0);
      }
    }
  }

  float* pb = partial + ((size_t)((b * NH + h) * SPLIT + s)) * 4096;
#pragma unroll
  for (int nf = 0; nf < 4; ++nf)
#pragma unroll
    for (int r = 0; r < 4; ++r)
      pb[(w * 16 + lg * 4 + r) * 64 + nf * 16 + l15] = dacc[nf][r];
}

// ---------------------------------------------------------------------------
// reduce split partials -> dots (scaled by 1/n2).
// ---------------------------------------------------------------------------
__global__ __launch_bounds__(256) void k_reduce(
    const float* __restrict__ partial, float* __restrict__ dots)
{
  const int idx = blockIdx.x * 256 + threadIdx.x;
  const int bh = idx >> 12;
  const int de = idx & 4095;
  const float* p = partial + (size_t)bh * SPLIT * 4096 + de;
  float s = 0.f;
#pragma unroll
  for (int i = 0; i < SPLIT; ++i) s += p[(size_t)i * 4096];
  dots[idx] = s * (1.f / (float)NTOK);
}

// ---------------------------------------------------------------------------
// tmp[b][r][c] = sum_j dots[b][r>>6][r&63][j] * Wout[(r>>6)*64+j][c]
// ---------------------------------------------------------------------------
__global__ __launch_bounds__(256) void k_bdwout(
    const float* __restrict__ dots, const float* __restrict__ Wout,
    float* __restrict__ tmp)
{
  const int bid = blockIdx.x;
  const int b = bid >> 7;
  const int r4 = (bid & 127) * 4;
  const int h = r4 >> 6;
  const int c = threadIdx.x;
  const float* dr = dots + (size_t)(b * NH + h) * 4096 + (size_t)(r4 & 63) * 64;
  float a0 = 0.f, a1 = 0.f, a2 = 0.f, a3 = 0.f;
#pragma unroll 8
  for (int j = 0; j < 64; ++j) {
    const float wv = Wout[(size_t)(h * 64 + j) * DIMX + c];
    a0 += dr[j] * wv;
    a1 += dr[64 + j] * wv;
    a2 += dr[128 + j] * wv;
    a3 += dr[192 + j] * wv;
  }
  float* tb = tmp + ((size_t)b * INNER + r4) * DIMX + c;
  tb[0] = a0; tb[DIMX] = a1; tb[2 * DIMX] = a2; tb[3 * DIMX] = a3;
}

// ---------------------------------------------------------------------------
// W_effT[b][c][r] (bf16) = sum_k Wq[r][k] * tmp[b][k][c]
// ---------------------------------------------------------------------------
__global__ __launch_bounds__(256) void k_weff(
    const float* __restrict__ Wq, const float* __restrict__ tmp,
    unsigned short* __restrict__ weffT)
{
  const int bid = blockIdx.x;
  const int b = bid >> 6;
  const int r4 = (bid & 63) * 4;
  const int c = threadIdx.x;
  const float* tb = tmp + (size_t)b * INNER * DIMX + c;
  float a0 = 0.f, a1 = 0.f, a2 = 0.f, a3 = 0.f;
#pragma unroll 8
  for (int k = 0; k < INNER; ++k) {
    const float t = tb[(size_t)k * DIMX];
    a0 += Wq[(size_t)(r4 + 0) * INNER + k] * t;
    a1 += Wq[(size_t)(r4 + 1) * INNER + k] * t;
    a2 += Wq[(size_t)(r4 + 2) * INNER + k] * t;
    a3 += Wq[(size_t)(r4 + 3) * INNER + k] * t;
  }
  unsigned short* wb = weffT + ((size_t)b * DIMX + c) * DIMX + r4;
  wb[0] = f2bf(a0); wb[1] = f2bf(a1); wb[2] = f2bf(a2); wb[3] = f2bf(a3);
}

// ---------------------------------------------------------------------------
// out[b] = x[b] @ W_eff[b] + bout via MFMA, double-buffered LDS W slices.
// grid = NB*128 = 512 blocks, 256 thr. Block: 64 tokens x 256 cols.
// ---------------------------------------------------------------------------
__global__ __launch_bounds__(256) void k_out_mfma(
    const float* __restrict__ x, const unsigned short* __restrict__ weffT,
    const float* __restrict__ bout, float* __restrict__ out)
{
  const int tid  = threadIdx.x;
  const int lane = tid & 63;
  const int w    = tid >> 6;
  const int l15  = lane & 15;
  const int lg   = lane >> 4;

  const int bid = blockIdx.x;
  const int mt = bid & 127;
  const int b  = bid >> 7;
  const int tok0 = mt * 64;

  __shared__ unsigned short wsl[2][256 * 36];   // k-slice: 256 cols x 32 k, pad 36

  // A-fragments: x row (tok0 + w*16 + l15), converted fp32->bf16.
  short8 afr[8];
  {
    const float* xr = x + ((size_t)b * NTOK + tok0 + w * 16 + l15) * DIMX + lg * 8;
#pragma unroll
    for (int kk = 0; kk < 8; ++kk) {
      float4 xa = *(const float4*)(xr + kk * 32);
      float4 xb = *(const float4*)(xr + kk * 32 + 4);
      short8 a;
      a[0] = (short)f2bf(xa.x); a[1] = (short)f2bf(xa.y);
      a[2] = (short)f2bf(xa.z); a[3] = (short)f2bf(xa.w);
      a[4] = (short)f2bf(xb.x); a[5] = (short)f2bf(xb.y);
      a[6] = (short)f2bf(xb.z); a[7] = (short)f2bf(xb.w);
      afr[kk] = a;
    }
  }

  f32x4 acc[16];
#pragma unroll
  for (int nf = 0; nf < 16; ++nf) acc[nf] = (f32x4){0.f, 0.f, 0.f, 0.f};

  const unsigned short* wb = weffT + (size_t)b * DIMX * DIMX + (size_t)tid * DIMX;

  // prologue: stage slice 0
  {
#pragma unroll
    for (int j = 0; j < 4; ++j) {
      short8 g = *(const short8*)(wb + j * 8);
      *(short8*)&wsl[0][tid * 36 + j * 8] = g;
    }
  }
  __syncthreads();

  for (int kk = 0; kk < 8; ++kk) {
    short8 g[4];
    if (kk < 7) {
#pragma unroll
      for (int j = 0; j < 4; ++j)
        g[j] = *(const short8*)(wb + (kk + 1) * 32 + j * 8);
    }
#pragma unroll
    for (int nf = 0; nf < 16; ++nf) {
      short8 b2 = *(const short8*)&wsl[kk & 1][(nf * 16 + l15) * 36 + lg * 8];
      acc[nf] = __builtin_amdgcn_mfma_f32_16x16x32_bf16(afr[kk], b2, acc[nf], 0, 0, 0);
    }
    if (kk < 7) {
#pragma unroll
      for (int j = 0; j < 4; ++j)
        *(short8*)&wsl[(kk + 1) & 1][tid * 36 + j * 8] = g[j];
    }
    __syncthreads();
  }

#pragma unroll
  for (int nf = 0; nf < 16; ++nf) {
    const float bias = bout[nf * 16 + l15];
#pragma unroll
    for (int r = 0; r < 4; ++r) {
      const int row = tok0 + w * 16 + lg * 4 + r;
      out[((size_t)b * NTOK + row) * DIMX + nf * 16 + l15] = acc[nf][r] + bias;
    }
  }
}

// ---------------------------------------------------------------------------
extern "C" void kernel_launch(void* const* d_in, const int* in_sizes, int n_in,
                              void* d_out, int out_size, void* d_ws, size_t ws_size,
                              hipStream_t stream) {
  const float* x    = (const float*)d_in[0];
  const float* z    = (const float*)d_in[1];
  const float* Wq   = (const float*)d_in[2];
  const float* Wkv  = (const float*)d_in[3];
  const float* Wout = (const float*)d_in[4];
  const float* bout = (const float*)d_in[5];
  float* out = (float*)d_out;

  float* ws      = (float*)d_ws;
  float* partial = ws;                                        // 512*4096 f = 8MB
  float* dots    = partial + (size_t)NB * NH * SPLIT * 4096;  // 131,072 f
  float* tmp     = dots + (size_t)NB * NH * 4096;             // 524,288 f
  unsigned short* wkvT  = (unsigned short*)(tmp + (size_t)NB * INNER * DIMX); // 0.5MB
  unsigned short* weffT = wkvT + (size_t)(2 * INNER) * DIMX;                  // 0.5MB
  // ws total ~11.5MB

  // z_bf16 lives in d_out's first 16MB (d_out is 32MB, fully rewritten by
  // k_out_mfma at the end; stream-ordered so no hazard).
  unsigned short* zbf = (unsigned short*)d_out;

  k_wkvT<<<64, 256, 0, stream>>>(Wkv, wkvT);
  k_zbf<<<2048, 256, 0, stream>>>(z, zbf);
  k_dots_mfma<<<NB * NH * SPLIT, 256, 0, stream>>>(zbf, wkvT, partial);
  k_reduce<<<512, 256, 0, stream>>>(partial, dots);
  k_bdwout<<<NB * 128, 256, 0, stream>>>(dots, Wout, tmp);
  k_weff<<<NB * 64, 256, 0, stream>>>(Wq, tmp, weffT);
  k_out_mfma<<<NB * 128, 256, 0, stream>>>(x, weffT, bout, out);
}